// Round 1
// baseline (308.225 us; speedup 1.0000x reference)
//
#include <hip/hip_runtime.h>
#include <cmath>

typedef __attribute__((ext_vector_type(8))) short short8;
typedef __attribute__((ext_vector_type(4))) float f32x4;
typedef __attribute__((ext_vector_type(4))) unsigned short us4;
typedef unsigned short u16;

#define BATCH 8192
#define HDIM  256
static constexpr size_t BH = (size_t)BATCH * HDIM;  // 2,097,152

__device__ __forceinline__ u16 f2bf(float f) {
    union { float f; unsigned u; } v; v.f = f;
    unsigned r = v.u + 0x7FFFu + ((v.u >> 16) & 1u);
    return (u16)(r >> 16);
}
__device__ __forceinline__ float bf2f(u16 u) {
    union { unsigned u; float f; } v; v.u = ((unsigned)u) << 16;
    return v.f;
}
__device__ __forceinline__ float wred(float v) {
#pragma unroll
    for (int o = 32; o > 0; o >>= 1) v += __shfl_xor(v, o);
    return v;
}
__device__ __forceinline__ float sigmoidf_(float x) {
    return 1.f / (1.f + __expf(-x));
}

// ---------------- weight conversion: pack all needed weights to bf16 ----------------
// dst layout (u16 units, 65536 per chunk):
//  c0: embed_w | c1..4: wtn[l] | c5..8: wsn[l] | c9..12: wt[l][512:768]
//  c13..16: ws[l][0:256] | c17..20: ws[l][512:768] | c21: out_w
__global__ __launch_bounds__(256) void convert_weights(
    const float* __restrict__ embed_w, const float* __restrict__ wtn,
    const float* __restrict__ wsn, const float* __restrict__ wt,
    const float* __restrict__ ws, const float* __restrict__ out_w,
    u16* __restrict__ dst)
{
    int idx = blockIdx.x * 256 + threadIdx.x;
    int e = idx * 4;
    if (e >= 22 * 65536) return;
    int c = e >> 16, o = e & 65535;
    const float* src;
    if (c == 0)      src = embed_w + o;
    else if (c < 5)  src = wtn + (size_t)(c - 1) * 65536 + o;
    else if (c < 9)  src = wsn + (size_t)(c - 5) * 65536 + o;
    else if (c < 13) src = wt + (size_t)(c - 9) * 768 * 256 + 512 * 256 + o;
    else if (c < 17) src = ws + (size_t)(c - 13) * 768 * 256 + o;
    else if (c < 21) src = ws + (size_t)(c - 17) * 768 * 256 + 512 * 256 + o;
    else             src = out_w + o;
    f32x4 v = *(const f32x4*)src;
    us4 r;
#pragma unroll
    for (int j = 0; j < 4; ++j) r[j] = f2bf(v[j]);
    *(us4*)(dst + e) = r;
}

// ---------------- GEMM: C[M,256] = A[M,256] @ W[256,256]^T + bias ----------------
// block = 256 thr (4 waves, 2x2), tile 128x64; per wave 64x32 via 4x2 mfma 16x16x32.
// ACT==0: store bf16; ACT==1: store f32 tanh (final output).
template<bool A_F32, int ACT>
__global__ __launch_bounds__(256) void gemm256(
    const void* __restrict__ Ap, const u16* __restrict__ W,
    const float* __restrict__ bias, void* __restrict__ Cp)
{
    int lane = threadIdx.x & 63;
    int wave = threadIdx.x >> 6;
    int wm = wave >> 1, wn = wave & 1;
    int row0 = blockIdx.x * 128 + wm * 64;
    int col0 = blockIdx.y * 64 + wn * 32;
    int lr = lane & 15;
    int kg = lane >> 4;

    f32x4 acc[4][2] = {};
    for (int k0 = 0; k0 < 256; k0 += 32) {
        int k = k0 + kg * 8;
        short8 a[4], b[2];
        if constexpr (A_F32) {
            const float* A = (const float*)Ap;
#pragma unroll
            for (int mt = 0; mt < 4; ++mt) {
                const float* p = A + (size_t)(row0 + mt * 16 + lr) * 256 + k;
                f32x4 lo = *(const f32x4*)p;
                f32x4 hi = *(const f32x4*)(p + 4);
                short8 t;
                t[0] = (short)f2bf(lo[0]); t[1] = (short)f2bf(lo[1]);
                t[2] = (short)f2bf(lo[2]); t[3] = (short)f2bf(lo[3]);
                t[4] = (short)f2bf(hi[0]); t[5] = (short)f2bf(hi[1]);
                t[6] = (short)f2bf(hi[2]); t[7] = (short)f2bf(hi[3]);
                a[mt] = t;
            }
        } else {
            const u16* A = (const u16*)Ap;
#pragma unroll
            for (int mt = 0; mt < 4; ++mt)
                a[mt] = *(const short8*)(A + (size_t)(row0 + mt * 16 + lr) * 256 + k);
        }
#pragma unroll
        for (int nt = 0; nt < 2; ++nt)
            b[nt] = *(const short8*)(W + (size_t)(col0 + nt * 16 + lr) * 256 + k);
#pragma unroll
        for (int mt = 0; mt < 4; ++mt)
#pragma unroll
            for (int nt = 0; nt < 2; ++nt)
                acc[mt][nt] = __builtin_amdgcn_mfma_f32_16x16x32_bf16(a[mt], b[nt], acc[mt][nt], 0, 0, 0);
    }
#pragma unroll
    for (int nt = 0; nt < 2; ++nt) {
        int n = col0 + nt * 16 + lr;
        float bn = bias[n];
#pragma unroll
        for (int mt = 0; mt < 4; ++mt) {
            int m0 = row0 + mt * 16 + kg * 4;
#pragma unroll
            for (int r = 0; r < 4; ++r) {
                float v = acc[mt][nt][r] + bn;
                if constexpr (ACT == 0) ((u16*)Cp)[(size_t)(m0 + r) * 256 + n] = f2bf(v);
                else                    ((float*)Cp)[(size_t)(m0 + r) * 256 + n] = tanhf(v);
            }
        }
    }
}

// ---------------- fused triple GEMM + gated combine ----------------
// t_s = Tf @ Wt3^T + bt3 ; s_g = Sf @ Ws1^T + bs1 ; s_s = Sf @ Ws3^T + bs3
// Sout = sig(s_g)*s_s + (1-sig(s_g))*t_s   (bf16)
__global__ __launch_bounds__(256) void gemm_fuse3(
    const u16* __restrict__ Tf, const u16* __restrict__ Sf,
    const u16* __restrict__ Wt3, const u16* __restrict__ Ws1, const u16* __restrict__ Ws3,
    const float* __restrict__ bt3, const float* __restrict__ bs1, const float* __restrict__ bs3,
    u16* __restrict__ Sout)
{
    int lane = threadIdx.x & 63;
    int wave = threadIdx.x >> 6;
    int wm = wave >> 1, wn = wave & 1;
    int row0 = blockIdx.x * 128 + wm * 64;
    int col0 = blockIdx.y * 64 + wn * 32;
    int lr = lane & 15;
    int kg = lane >> 4;

    f32x4 accT[4][2] = {}, accG[4][2] = {}, accS[4][2] = {};
    for (int k0 = 0; k0 < 256; k0 += 32) {
        int k = k0 + kg * 8;
        short8 at[4], as[4], bT[2], bG[2], bS[2];
#pragma unroll
        for (int mt = 0; mt < 4; ++mt) {
            size_t off = (size_t)(row0 + mt * 16 + lr) * 256 + k;
            at[mt] = *(const short8*)(Tf + off);
            as[mt] = *(const short8*)(Sf + off);
        }
#pragma unroll
        for (int nt = 0; nt < 2; ++nt) {
            size_t off = (size_t)(col0 + nt * 16 + lr) * 256 + k;
            bT[nt] = *(const short8*)(Wt3 + off);
            bG[nt] = *(const short8*)(Ws1 + off);
            bS[nt] = *(const short8*)(Ws3 + off);
        }
#pragma unroll
        for (int mt = 0; mt < 4; ++mt)
#pragma unroll
            for (int nt = 0; nt < 2; ++nt) {
                accT[mt][nt] = __builtin_amdgcn_mfma_f32_16x16x32_bf16(at[mt], bT[nt], accT[mt][nt], 0, 0, 0);
                accG[mt][nt] = __builtin_amdgcn_mfma_f32_16x16x32_bf16(as[mt], bG[nt], accG[mt][nt], 0, 0, 0);
                accS[mt][nt] = __builtin_amdgcn_mfma_f32_16x16x32_bf16(as[mt], bS[nt], accS[mt][nt], 0, 0, 0);
            }
    }
#pragma unroll
    for (int nt = 0; nt < 2; ++nt) {
        int n = col0 + nt * 16 + lr;
        float b1 = bt3[n], b2 = bs1[n], b3 = bs3[n];
#pragma unroll
        for (int mt = 0; mt < 4; ++mt) {
            int m0 = row0 + mt * 16 + kg * 4;
#pragma unroll
            for (int r = 0; r < 4; ++r) {
                float g = sigmoidf_(accG[mt][nt][r] + b2);
                float v = g * (accS[mt][nt][r] + b3) + (1.f - g) * (accT[mt][nt][r] + b1);
                Sout[(size_t)(m0 + r) * 256 + n] = f2bf(v);
            }
        }
    }
}

// ---------------- fused attention (temporal + spatial) + gating ----------------
// one wave per batch row; lane covers h = 4*lane .. 4*lane+3
__global__ __launch_bounds__(256) void attn_fuse(
    const float* __restrict__ t_att, const float* __restrict__ s_att,
    const u16* __restrict__ S_hist,
    const u16* __restrict__ s_next, const u16* __restrict__ t_next,
    u16* __restrict__ T_fus, u16* __restrict__ S_fus, int layer)
{
    const int b = blockIdx.x * 4 + (threadIdx.x >> 6);
    const int lane = threadIdx.x & 63;
    const size_t rowoff = (size_t)b * 256 + lane * 4;
    const float scale = 0.0625f;  // 1/sqrt(256)

    us4 snu = *(const us4*)(s_next + rowoff);
    us4 tnu = *(const us4*)(t_next + rowoff);
    us4 scu = *(const us4*)(S_hist + (size_t)layer * BH + rowoff);
    float sn[4], tn[4], Sc[4];
#pragma unroll
    for (int j = 0; j < 4; ++j) { sn[j] = bf2f(snu[j]); tn[j] = bf2f(tnu[j]); Sc[j] = bf2f(scu[j]); }

    const float* ta = t_att + (size_t)layer * 8 * BH + rowoff;
    const float* sa = s_att + (size_t)layer * 8 * BH + rowoff;

    // temporal logits: keys = s_att[i,1:] ++ [S]
    float lt[8];
#pragma unroll
    for (int kk = 0; kk < 7; ++kk) {
        f32x4 v = *(const f32x4*)(sa + (size_t)(kk + 1) * BH);
        lt[kk] = wred(v[0] * sn[0] + v[1] * sn[1] + v[2] * sn[2] + v[3] * sn[3]) * scale;
    }
    lt[7] = wred(Sc[0] * sn[0] + Sc[1] * sn[1] + Sc[2] * sn[2] + Sc[3] * sn[3]) * scale;

    float m = lt[0];
#pragma unroll
    for (int kk = 1; kk < 8; ++kk) m = fmaxf(m, lt[kk]);
    float w8[8], den = 0.f;
#pragma unroll
    for (int kk = 0; kk < 8; ++kk) { w8[kk] = __expf(lt[kk] - m); den += w8[kk]; }
    float inv = 1.f / den;

    // T_trend + T_fusion
    float Tt[4] = {0.f, 0.f, 0.f, 0.f}, Tl[4];
#pragma unroll
    for (int kk = 0; kk < 8; ++kk) {
        f32x4 v = *(const f32x4*)(ta + (size_t)kk * BH);
#pragma unroll
        for (int j = 0; j < 4; ++j) Tt[j] += w8[kk] * v[j];
        if (kk == 7) { Tl[0] = v[0]; Tl[1] = v[1]; Tl[2] = v[2]; Tl[3] = v[3]; }
    }
    us4 ot;
#pragma unroll
    for (int j = 0; j < 4; ++j) {
        float g = sigmoidf_(tn[j]);
        ot[j] = f2bf(Tl[j] * g + (1.f - g) * Tt[j] * inv);
    }
    *(us4*)(T_fus + rowoff) = ot;

    // spatial attention: t_sp = [zeros x (7-layer), t_att[0,7] .. t_att[layer,7]]
    //                    s_sp = [zeros x (7-layer), S_hist[0] .. S_hist[layer]]
    // online softmax; zero entries contribute logit 0, value 0.
    float msx = 0.f;                       // max starts at 0 (>=3 zero logits always present)
    float dens = (float)(7 - layer);       // zero entries: exp(0-0)=1 each
    float St[4] = {0.f, 0.f, 0.f, 0.f};
    for (int jj = 0; jj <= layer; ++jj) {
        f32x4 v = *(const f32x4*)(t_att + ((size_t)jj * 8 + 7) * BH + rowoff);
        float p = wred(v[0] * tn[0] + v[1] * tn[1] + v[2] * tn[2] + v[3] * tn[3]) * scale;
        us4 shu = *(const us4*)(S_hist + (size_t)jj * BH + rowoff);
        if (p > msx) {  // wave-uniform branch (p is post-reduction)
            float c = __expf(msx - p);
            dens *= c; St[0] *= c; St[1] *= c; St[2] *= c; St[3] *= c;
            msx = p;
        }
        float w = __expf(p - msx);
        dens += w;
#pragma unroll
        for (int j = 0; j < 4; ++j) St[j] += w * bf2f(shu[j]);
    }
    float invs = 1.f / dens;
    us4 os;
#pragma unroll
    for (int j = 0; j < 4; ++j) {
        float g = sigmoidf_(sn[j]);
        os[j] = f2bf(Sc[j] * g + (1.f - g) * St[j] * invs);
    }
    *(us4*)(S_fus + rowoff) = os;
}

extern "C" void kernel_launch(void* const* d_in, const int* in_sizes, int n_in,
                              void* d_out, int out_size, void* d_ws, size_t ws_size,
                              hipStream_t stream)
{
    (void)in_sizes; (void)n_in; (void)out_size; (void)ws_size;
    const float* x       = (const float*)d_in[0];
    const float* t_att   = (const float*)d_in[1];
    const float* s_att   = (const float*)d_in[2];
    const float* embed_w = (const float*)d_in[3];
    const float* embed_b = (const float*)d_in[4];
    const float* wtn     = (const float*)d_in[5];
    const float* btn     = (const float*)d_in[6];
    const float* wsn     = (const float*)d_in[7];
    const float* bsn     = (const float*)d_in[8];
    const float* wt      = (const float*)d_in[9];
    const float* bt      = (const float*)d_in[10];
    const float* ws_in   = (const float*)d_in[11];
    const float* bs      = (const float*)d_in[12];
    const float* out_w   = (const float*)d_in[13];
    const float* out_b   = (const float*)d_in[14];

    u16* wsp     = (u16*)d_ws;
    u16* Wbf     = wsp;                         // 22 * 65536 u16
    u16* S_hist  = wsp + (size_t)22 * 65536;    // 5 * BH u16
    u16* s_next  = S_hist + 5 * BH;
    u16* t_next  = s_next + BH;
    u16* T_fus   = t_next + BH;
    u16* S_fus   = T_fus + BH;

    u16* embed_w_bf = Wbf;
    u16* wtn_bf     = Wbf + (size_t)1  * 65536;
    u16* wsn_bf     = Wbf + (size_t)5  * 65536;
    u16* wt3_bf     = Wbf + (size_t)9  * 65536;
    u16* ws1_bf     = Wbf + (size_t)13 * 65536;
    u16* ws3_bf     = Wbf + (size_t)17 * 65536;
    u16* out_w_bf   = Wbf + (size_t)21 * 65536;

    convert_weights<<<1408, 256, 0, stream>>>(embed_w, wtn, wsn, wt, ws_in, out_w, Wbf);

    dim3 gg(BATCH / 128, HDIM / 64);

    // S0 = x @ embed_w^T + embed_b
    gemm256<true, 0><<<gg, 256, 0, stream>>>(x, embed_w_bf, embed_b, S_hist);

    for (int i = 0; i < 4; ++i) {
        // s_next = S @ wsn[i]^T + bsn[i]   (A is bf16 S_hist[i])
        gemm256<false, 0><<<gg, 256, 0, stream>>>(S_hist + (size_t)i * BH,
                                                  wsn_bf + (size_t)i * 65536,
                                                  bsn + i * 256, s_next);
        // t_next = T_last @ wtn[i]^T + btn[i]   (A is f32 t_att[i,7])
        gemm256<true, 0><<<gg, 256, 0, stream>>>(t_att + ((size_t)i * 8 + 7) * BH,
                                                 wtn_bf + (size_t)i * 65536,
                                                 btn + i * 256, t_next);
        // attention + gated fusion -> T_fus, S_fus
        attn_fuse<<<BATCH / 4, 256, 0, stream>>>(t_att, s_att, S_hist, s_next, t_next,
                                                 T_fus, S_fus, i);
        // S_{i+1} = sig(s_g)*s_s + (1-sig(s_g))*t_s
        gemm_fuse3<<<gg, 256, 0, stream>>>(T_fus, S_fus,
                                           wt3_bf + (size_t)i * 65536,
                                           ws1_bf + (size_t)i * 65536,
                                           ws3_bf + (size_t)i * 65536,
                                           bt + i * 768 + 512, bs + i * 768, bs + i * 768 + 512,
                                           S_hist + (size_t)(i + 1) * BH);
    }

    // out = tanh(S @ out_w^T + out_b), f32
    gemm256<false, 1><<<gg, 256, 0, stream>>>(S_hist + (size_t)4 * BH, out_w_bf, out_b, d_out);
}